// Round 12
// baseline (233.951 us; speedup 1.0000x reference)
//
#include <hip/hip_runtime.h>
#include <hip/hip_bf16.h>

#define DD 128    // feature dim
#define HH 16     // hidden dim
#define BW 128    // bucket width (nodes per bucket) = 1<<7
#define NBMAX 1024
#define SCAP 4096      // LDS slice cap in sortagg (avg slice 2048, max ~2300)

// bf16x2 pack/unpack (RNE)
__device__ __forceinline__ float lo16(unsigned u) { return __uint_as_float(u << 16); }
__device__ __forceinline__ float hi16(unsigned u) { return __uint_as_float(u & 0xffff0000u); }
__device__ __forceinline__ unsigned b16(float f) {
    unsigned u = __float_as_uint(f);
    return (u + 0x7fffu + ((u >> 16) & 1u)) >> 16;
}
__device__ __forceinline__ unsigned pack2(float a, float b) {
    return b16(a) | (b16(b) << 16);
}

// ---------------------------------------------------------------------------
// K1: bucket histogram (4096 edges/block) + classifier-collapse prep (last
// block).
//   wsu[0..15]  = w2_l[j,:].wc[:128]    wsu[16..31] = w2_l[j,:].wc[128:]
//   wsu[32..47] = w2_r[j,:].wc[:128]    wsu[48..63] = w2_r[j,:].wc[128:]
//   wsu[64] = b2.wc[:128] + bc ;  wsu[65] = b2.wc[128:]
// ---------------------------------------------------------------------------
__global__ __launch_bounds__(256) void k_bcount(const int* __restrict__ dst,
                                                int* __restrict__ bcnt,
                                                int E4, int NB, int cblocks,
                                                const float* __restrict__ w2l,
                                                const float* __restrict__ w2r,
                                                const float* __restrict__ b2v,
                                                const float* __restrict__ wc,
                                                const float* __restrict__ bc,
                                                float* __restrict__ wsu) {
    if (blockIdx.x == (unsigned)cblocks) {      // prep block
        int t = threadIdx.x;
        if (t < 64) {
            int k = t >> 4, j = t & 15;
            const float* W = (k < 2) ? w2l : w2r;
            int off = (k & 1) * DD;
            float s = 0.f;
            for (int d = 0; d < DD; ++d) s += W[j * DD + d] * wc[off + d];
            wsu[k * 16 + j] = s;
        } else if (t == 64) {
            float s = bc[0];
            for (int d = 0; d < DD; ++d) s += b2v[d] * wc[d];
            wsu[64] = s;
        } else if (t == 65) {
            float s = 0.f;
            for (int d = 0; d < DD; ++d) s += b2v[d] * wc[DD + d];
            wsu[65] = s;
        }
        return;
    }
    __shared__ int hist[NBMAX];
    for (int i = threadIdx.x; i < NB; i += 256) hist[i] = 0;
    __syncthreads();
    int base = blockIdx.x * 1024;
#pragma unroll
    for (int k = 0; k < 4; ++k) {
        int i4 = base + k * 256 + threadIdx.x;
        if (i4 < E4) {
            int4 d = ((const int4*)dst)[i4];
            atomicAdd(&hist[d.x >> 7], 1);
            atomicAdd(&hist[d.y >> 7], 1);
            atomicAdd(&hist[d.z >> 7], 1);
            atomicAdd(&hist[d.w >> 7], 1);
        }
    }
    __syncthreads();
    for (int i = threadIdx.x; i < NB; i += 256) {
        int h = hist[i];
        if (h) atomicAdd(&bcnt[i], h);
    }
}

// ---------------------------------------------------------------------------
// K2: exclusive scan over NB bucket counts -> bstart (+[NB]=E), gcursor;
// also nodestart[N] = E. Single block of 1024.
// ---------------------------------------------------------------------------
__global__ __launch_bounds__(1024) void k_bscan(const int* __restrict__ bcnt,
                                                int* __restrict__ bstart,
                                                int* __restrict__ gcursor,
                                                int* __restrict__ nodestart,
                                                int NB, int N, int E) {
    __shared__ int sa[1024];
    __shared__ int sb[1024];
    int t = threadIdx.x;
    int v = (t < NB) ? bcnt[t] : 0;
    sa[t] = v;
    __syncthreads();
    int* cur = sa;
    int* nxt = sb;
    for (int off = 1; off < 1024; off <<= 1) {
        int xv = cur[t];
        if (t >= off) xv += cur[t - off];
        nxt[t] = xv;
        __syncthreads();
        int* tmp = cur; cur = nxt; nxt = tmp;
    }
    if (t < NB) {
        int excl = cur[t] - v;
        bstart[t] = excl;
        gcursor[t] = excl;
    }
    if (t == 0) {
        bstart[NB] = cur[1023];
        nodestart[N] = E;
    }
}

// ---------------------------------------------------------------------------
// K3: bucketed scatter (4096 edges/block). LDS hist -> bulk range
// reservation -> packed entries (local<<20 | src) into per-bucket ranges.
// ---------------------------------------------------------------------------
__global__ __launch_bounds__(256) void k_bscatter(const int* __restrict__ src,
                                                  const int* __restrict__ dst,
                                                  int* __restrict__ gcursor,
                                                  int* __restrict__ packed,
                                                  int E4, int NB) {
    __shared__ int hist[NBMAX];
    __shared__ int cur[NBMAX];
    for (int i = threadIdx.x; i < NB; i += 256) hist[i] = 0;
    __syncthreads();
    int base = blockIdx.x * 1024;
    int4 dreg[4];
#pragma unroll
    for (int k = 0; k < 4; ++k) {
        int i4 = base + k * 256 + threadIdx.x;
        if (i4 < E4) {
            int4 d = ((const int4*)dst)[i4];
            dreg[k] = d;
            atomicAdd(&hist[d.x >> 7], 1);
            atomicAdd(&hist[d.y >> 7], 1);
            atomicAdd(&hist[d.z >> 7], 1);
            atomicAdd(&hist[d.w >> 7], 1);
        }
    }
    __syncthreads();
    for (int i = threadIdx.x; i < NB; i += 256) {
        int hv = hist[i];
        cur[i] = hv ? atomicAdd(&gcursor[i], hv) : 0;
    }
    __syncthreads();
#pragma unroll
    for (int k = 0; k < 4; ++k) {
        int i4 = base + k * 256 + threadIdx.x;
        if (i4 < E4) {
            int4 sv = ((const int4*)src)[i4];
            int4 d = dreg[k];
            int p;
            p = atomicAdd(&cur[d.x >> 7], 1); packed[p] = ((d.x & 127) << 20) | sv.x;
            p = atomicAdd(&cur[d.y >> 7], 1); packed[p] = ((d.y & 127) << 20) | sv.y;
            p = atomicAdd(&cur[d.z >> 7], 1); packed[p] = ((d.z & 127) << 20) | sv.z;
            p = atomicAdd(&cur[d.w >> 7], 1); packed[p] = ((d.w & 127) << 20) | sv.w;
        }
    }
}

// ---------------------------------------------------------------------------
// K4: y1 = x @ w1_l (bf16 out), z1 = x @ w1_r (f32 out)
// Weights-in-registers scheme: lane = (dg,seg); dg in [0,16) owns 8 d's,
// seg in [0,4) owns 4 output cols. Weights preloaded once (64 f4 regs/lane
// across wave). Per row: 2 global f4 x-reads (wave-unique 512 B, L1
// broadcast over segs), 64 FMAs, 8x4 shfl_xor reduce over dg, lanes dg==0
// write. Zero LDS -> no LDS-return-BW wall. 1-deep row prefetch.
// ---------------------------------------------------------------------------
__global__ __launch_bounds__(256) void k_xform(const float* __restrict__ x,
                                               const float* __restrict__ w1l,
                                               const float* __restrict__ w1r,
                                               unsigned* __restrict__ y1b,
                                               float* __restrict__ z1, int N) {
    const int tid  = threadIdx.x;
    const int lane = tid & 63;
    const int dg   = lane >> 2;   // d-group: d = dg*8 .. dg*8+8
    const int seg  = lane & 3;    // output float4 column
    const int wid  = (int)((blockIdx.x * 256 + tid) >> 6);
    const int nw   = (int)((gridDim.x * 256) >> 6);

    // preload weights for this lane's (dg, seg)
    float4 WL[8], WR[8];
#pragma unroll
    for (int i = 0; i < 8; ++i) {
        int d = dg * 8 + i;
        WL[i] = ((const float4*)w1l)[d * 4 + seg];
        WR[i] = ((const float4*)w1r)[d * 4 + seg];
    }

    const float4* xg = (const float4*)x;
    int row = wid;
    float4 c0 = {0,0,0,0}, c1 = {0,0,0,0};
    if (row < N) {
        c0 = xg[(size_t)row * 32 + dg * 2 + 0];
        c1 = xg[(size_t)row * 32 + dg * 2 + 1];
    }
    while (row < N) {
        int nrow = row + nw;
        float4 n0 = {0,0,0,0}, n1 = {0,0,0,0};
        if (nrow < N) {                      // prefetch next row
            n0 = xg[(size_t)nrow * 32 + dg * 2 + 0];
            n1 = xg[(size_t)nrow * 32 + dg * 2 + 1];
        }
        float4 ya = {0,0,0,0}, za = {0,0,0,0};
        float xs[8] = {c0.x, c0.y, c0.z, c0.w, c1.x, c1.y, c1.z, c1.w};
#pragma unroll
        for (int i = 0; i < 8; ++i) {
            float xv = xs[i];
            ya.x += xv * WL[i].x; ya.y += xv * WL[i].y;
            ya.z += xv * WL[i].z; ya.w += xv * WL[i].w;
            za.x += xv * WR[i].x; za.y += xv * WR[i].y;
            za.z += xv * WR[i].z; za.w += xv * WR[i].w;
        }
        // reduce over dg (lane bits 2..5)
#pragma unroll
        for (int m = 4; m <= 32; m <<= 1) {
            ya.x += __shfl_xor(ya.x, m, 64); ya.y += __shfl_xor(ya.y, m, 64);
            ya.z += __shfl_xor(ya.z, m, 64); ya.w += __shfl_xor(ya.w, m, 64);
            za.x += __shfl_xor(za.x, m, 64); za.y += __shfl_xor(za.y, m, 64);
            za.z += __shfl_xor(za.z, m, 64); za.w += __shfl_xor(za.w, m, 64);
        }
        if (dg == 0) {
            uint2 yp; yp.x = pack2(ya.x, ya.y); yp.y = pack2(ya.z, ya.w);
            ((uint2*)y1b)[(size_t)row * 4 + seg] = yp;
            ((float4*)z1)[(size_t)row * 4 + seg] = za;
        }
        row = nrow; c0 = n0; c1 = n1;
    }
}

// ---------------------------------------------------------------------------
// K5: one block per bucket.
//   Phase A: counting-sort the bucket slice in LDS, write nodestart + csr.
//   Phase B: layer-1 mean for the bucket's 128 nodes from the LDS-sorted
//            slice, gathering bf16 y1 (8 B/gather):
//            h = relu(mean(y1[nbrs]) + b1 + z1), h stored bf16.
// Global fallback for oversized buckets.
// ---------------------------------------------------------------------------
__global__ __launch_bounds__(256) void k_sortagg(const int* __restrict__ packed,
                                                 const int* __restrict__ bstart,
                                                 int* __restrict__ nodestart,
                                                 int* __restrict__ csr,
                                                 const unsigned* __restrict__ y1b,
                                                 const float* __restrict__ z1,
                                                 const float* __restrict__ b1,
                                                 unsigned* __restrict__ hb, int N) {
    __shared__ int buf[SCAP];
    __shared__ int sbuf[SCAP];
    __shared__ int hist[BW];
    __shared__ int exs[BW];
    __shared__ int curs[BW];
    __shared__ int wtot;
    const int tid = threadIdx.x;
    const int b = blockIdx.x;
    const int st = bstart[b], en = bstart[b + 1], cnt = en - st;
    const bool inlds = (cnt <= SCAP);

    if (tid < BW) hist[tid] = 0;
    __syncthreads();
    if (inlds) {
        for (int i = tid; i < cnt; i += 256) {
            int e = packed[st + i];
            buf[i] = e;
            atomicAdd(&hist[e >> 20], 1);
        }
    } else {
        for (int i = tid; i < cnt; i += 256)
            atomicAdd(&hist[packed[st + i] >> 20], 1);
    }
    __syncthreads();

    int v = 0, s = 0;
    if (tid < BW) {
        int lane = tid & 63;
        v = hist[tid];
        s = v;
#pragma unroll
        for (int off = 1; off < 64; off <<= 1) {
            int u = __shfl_up(s, off, 64);
            if (lane >= off) s += u;
        }
        if (tid == 63) wtot = s;
    }
    __syncthreads();
    if (tid < BW) {
        int ex = s - v + ((tid >= 64) ? wtot : 0);
        exs[tid] = ex;
        curs[tid] = ex;
        int node = (b << 7) + tid;
        if (node < N) nodestart[node] = st + ex;
    }
    __syncthreads();

    if (inlds) {
        for (int i = tid; i < cnt; i += 256) {
            int e = buf[i];
            int p = atomicAdd(&curs[e >> 20], 1);
            sbuf[p] = e & 0xFFFFF;
        }
        __syncthreads();
        for (int i = tid; i < cnt; i += 256) csr[st + i] = sbuf[i];  // coalesced
    } else {
        for (int i = tid; i < cnt; i += 256) {
            int e = packed[st + i];
            int p = atomicAdd(&curs[e >> 20], 1);
            csr[st + p] = e & 0xFFFFF;
        }
        __threadfence_block();
        __syncthreads();
    }

    // ---- Phase B: aggregate 128 nodes (4 lanes/node, 2 halves) ----
    const uint2* f2 = (const uint2*)y1b;
#pragma unroll
    for (int half = 0; half < 2; ++half) {
        int l = (tid >> 2) + half * 64;
        int seg = tid & 3;
        int node = (b << 7) + l;
        if (node < N) {
            int s0 = exs[l], c = hist[l];
            float ax = 0.f, ay = 0.f, az = 0.f, aw = 0.f;
            int k = 0;
            if (inlds) {
                for (; k + 4 <= c; k += 4) {
                    uint2 a = f2[(size_t)(sbuf[s0 + k]     * 4 + seg)];
                    uint2 bv = f2[(size_t)(sbuf[s0 + k + 1] * 4 + seg)];
                    uint2 cv = f2[(size_t)(sbuf[s0 + k + 2] * 4 + seg)];
                    uint2 dv = f2[(size_t)(sbuf[s0 + k + 3] * 4 + seg)];
                    ax += (lo16(a.x) + lo16(bv.x)) + (lo16(cv.x) + lo16(dv.x));
                    ay += (hi16(a.x) + hi16(bv.x)) + (hi16(cv.x) + hi16(dv.x));
                    az += (lo16(a.y) + lo16(bv.y)) + (lo16(cv.y) + lo16(dv.y));
                    aw += (hi16(a.y) + hi16(bv.y)) + (hi16(cv.y) + hi16(dv.y));
                }
                for (; k < c; ++k) {
                    uint2 a = f2[(size_t)(sbuf[s0 + k] * 4 + seg)];
                    ax += lo16(a.x); ay += hi16(a.x);
                    az += lo16(a.y); aw += hi16(a.y);
                }
            } else {
                const int* ids = csr + st + s0;
                for (; k + 4 <= c; k += 4) {
                    uint2 a = f2[(size_t)(ids[k]     * 4 + seg)];
                    uint2 bv = f2[(size_t)(ids[k + 1] * 4 + seg)];
                    uint2 cv = f2[(size_t)(ids[k + 2] * 4 + seg)];
                    uint2 dv = f2[(size_t)(ids[k + 3] * 4 + seg)];
                    ax += (lo16(a.x) + lo16(bv.x)) + (lo16(cv.x) + lo16(dv.x));
                    ay += (hi16(a.x) + hi16(bv.x)) + (hi16(cv.x) + hi16(dv.x));
                    az += (lo16(a.y) + lo16(bv.y)) + (lo16(cv.y) + lo16(dv.y));
                    aw += (hi16(a.y) + hi16(bv.y)) + (hi16(cv.y) + hi16(dv.y));
                }
                for (; k < c; ++k) {
                    uint2 a = f2[(size_t)(ids[k] * 4 + seg)];
                    ax += lo16(a.x); ay += hi16(a.x);
                    az += lo16(a.y); aw += hi16(a.y);
                }
            }
            float inv = 1.f / fmaxf((float)c, 1.f);
            size_t o = (size_t)node * 4 + seg;
            float4 z = ((const float4*)z1)[o];
            float4 bb = ((const float4*)b1)[seg];
            float hx = fmaxf(ax * inv + bb.x + z.x, 0.f);
            float hy = fmaxf(ay * inv + bb.y + z.y, 0.f);
            float hz = fmaxf(az * inv + bb.z + z.z, 0.f);
            float hw = fmaxf(aw * inv + bb.w + z.w, 0.f);
            uint2 hp; hp.x = pack2(hx, hy); hp.y = pack2(hz, hw);
            ((uint2*)hb)[o] = hp;
        }
    }
}

// ---------------------------------------------------------------------------
// K6: fused layer-2 on-demand aggregation + pair logits + BCE + final mean
// (ticket). 8 lanes per pair: slot s=sub>>2 (article), seg=sub&3. Gathers
// bf16 h (8 B per edge per lane).
// ---------------------------------------------------------------------------
__global__ __launch_bounds__(256) void k_pair(const unsigned* __restrict__ hb,
                                              const int* __restrict__ csr,
                                              const int* __restrict__ nodestart,
                                              const int* __restrict__ a1,
                                              const int* __restrict__ a2,
                                              const int* __restrict__ labels,
                                              const float* __restrict__ wsu,
                                              float* __restrict__ out_logits,
                                              float* __restrict__ lacc,
                                              int* __restrict__ ticket,
                                              float* __restrict__ out0,
                                              int B, float invB) {
    __shared__ float lred[32];
    int t = blockIdx.x * 256 + threadIdx.x;
    int p = t >> 3, sub = t & 7;
    int s = sub >> 2, seg = sub & 3;
    int g = threadIdx.x >> 3;
    const uint2* h2 = (const uint2*)hb;
    const float4* wsu4 = (const float4*)wsu;

    float myloss = 0.f;
    if (p < B) {
        int node = s ? a2[p] : a1[p];
        int st = nodestart[node], en = nodestart[node + 1];
        float ax = 0.f, ay = 0.f, az = 0.f, aw = 0.f;
        int k = st;
        for (; k + 2 <= en; k += 2) {
            uint2 a = h2[(size_t)(csr[k]     * 4 + seg)];
            uint2 b = h2[(size_t)(csr[k + 1] * 4 + seg)];
            ax += lo16(a.x) + lo16(b.x); ay += hi16(a.x) + hi16(b.x);
            az += lo16(a.y) + lo16(b.y); aw += hi16(a.y) + hi16(b.y);
        }
        if (k < en) {
            uint2 a = h2[(size_t)(csr[k] * 4 + seg)];
            ax += lo16(a.x); ay += hi16(a.x);
            az += lo16(a.y); aw += hi16(a.y);
        }
        float inv = 1.f / fmaxf((float)(en - st), 1.f);
        float4 ul = wsu4[s * 4 + seg];
        float4 ur = wsu4[8 + s * 4 + seg];
        uint2 hn = h2[(size_t)node * 4 + seg];
        float v = (ax * ul.x + ay * ul.y + az * ul.z + aw * ul.w) * inv
                + (lo16(hn.x) * ur.x + hi16(hn.x) * ur.y
                 + lo16(hn.y) * ur.z + hi16(hn.y) * ur.w);
#pragma unroll
        for (int off = 4; off; off >>= 1) v += __shfl_xor(v, off, 8);
        if (sub == 0) {
            float l = v + wsu[64] + wsu[65];
            out_logits[p] = l;
            float y = (float)labels[p];
            myloss = fmaxf(l, 0.f) - l * y + log1pf(expf(-fabsf(l)));
        }
    }
    if (sub == 0) lred[g] = myloss;
    __syncthreads();
    if (threadIdx.x == 0) {
        float ssum = 0.f;
#pragma unroll
        for (int k = 0; k < 32; ++k) ssum += lred[k];
        atomicAdd(lacc, ssum);
        __threadfence();
        int tk = atomicAdd(ticket, 1);
        if (tk == (int)gridDim.x - 1) {
            __threadfence();
            float total = atomicAdd(lacc, 0.f);
            out0[0] = total * invB;
        }
    }
}

// ---------------------------------------------------------------------------
extern "C" void kernel_launch(void* const* d_in, const int* in_sizes, int n_in,
                              void* d_out, int out_size, void* d_ws, size_t ws_size,
                              hipStream_t stream) {
    const float* x    = (const float*)d_in[0];
    const float* w1l  = (const float*)d_in[1];
    const float* b1   = (const float*)d_in[2];
    const float* w1r  = (const float*)d_in[3];
    const float* w2l  = (const float*)d_in[4];
    const float* b2v  = (const float*)d_in[5];
    const float* w2r  = (const float*)d_in[6];
    const float* wc   = (const float*)d_in[7];
    const float* bc   = (const float*)d_in[8];
    const int*   ei   = (const int*)d_in[9];
    const int*   a1   = (const int*)d_in[10];
    const int*   a2   = (const int*)d_in[11];
    const int*   lab  = (const int*)d_in[12];

    const int N = in_sizes[0] / DD;
    const int E = in_sizes[9] / 2;
    const int B = in_sizes[10];
    const int NB = (N + BW - 1) / BW;       // 782 for N=100000 (needs N < 2^20)

    const int* src = ei;
    const int* dst = ei + E;

    // workspace layout
    char* ws = (char*)d_ws;
    float*    wsu    = (float*)ws;                            // 512 B
    unsigned* y1b    = (unsigned*)(ws + 512);                 // [N,16] bf16 (32 B/row)
    unsigned* hb     = (unsigned*)(ws + 512 + (size_t)N * 32);
    float*    z1     = (float*)   (ws + 512 + (size_t)N * 64);
    int*      packed = (int*)     (ws + 512 + (size_t)N * 128);
    int*      csr    = (int*)     (ws + 512 + (size_t)N * 128 + (size_t)E * 4);
    char*     p4     = ws + 512 + (size_t)N * 128 + 2 * (size_t)E * 4;
    int*   nodest  = (int*)p4;                               // [N+1]
    int*   bstart  = (int*)(p4 + ((size_t)N + 1) * 4);       // [NB+1]
    int*   gcursor = (int*)(p4 + ((size_t)N + 1) * 4 + ((size_t)NB + 1) * 4);  // [NB]
    int*   bcnt    = (int*)(p4 + ((size_t)N + 1) * 4 + (2 * (size_t)NB + 1) * 4); // [NB] zeroed
    float* lacc    = (float*)(p4 + ((size_t)N + 1) * 4 + (3 * (size_t)NB + 1) * 4);// zeroed
    int*   ticket  = (int*)((char*)lacc + 4);                // zeroed

    float* out = (float*)d_out;       // out[0] = loss, out[1..B] = logits

    hipMemsetAsync((void*)bcnt, 0, (size_t)NB * 4 + 8, stream);

    const int E4 = E / 4;
    const int cblocks = (E4 + 1023) / 1024;          // 4096 edges per chunk

    k_bcount<<<cblocks + 1, 256, 0, stream>>>(dst, bcnt, E4, NB, cblocks,
                                              w2l, w2r, b2v, wc, bc, wsu);
    k_bscan<<<1, 1024, 0, stream>>>(bcnt, bstart, gcursor, nodest, NB, N, E);
    k_bscatter<<<cblocks, 256, 0, stream>>>(src, dst, gcursor, packed, E4, NB);

    k_xform<<<1024, 256, 0, stream>>>(x, w1l, w1r, y1b, z1, N);

    k_sortagg<<<NB, 256, 0, stream>>>(packed, bstart, nodest, csr, y1b, z1, b1, hb, N);

    k_pair<<<(B * 8 + 255) / 256, 256, 0, stream>>>(hb, csr, nodest, a1, a2, lab, wsu,
                                                    out + 1, lacc, ticket, out,
                                                    B, 1.0f / (float)B);
}

// Round 13
// 206.661 us; speedup vs baseline: 1.1321x; 1.1321x over previous
//
#include <hip/hip_runtime.h>
#include <hip/hip_bf16.h>

#define DD 128    // feature dim
#define HH 16     // hidden dim
#define BW 128    // bucket width (nodes per bucket) = 1<<7
#define NBMAX 1024
#define SCAP 4096      // LDS slice cap in sortagg (avg slice 2048, max ~2300)

// bf16x2 pack/unpack (RNE)
__device__ __forceinline__ float lo16(unsigned u) { return __uint_as_float(u << 16); }
__device__ __forceinline__ float hi16(unsigned u) { return __uint_as_float(u & 0xffff0000u); }
__device__ __forceinline__ unsigned b16(float f) {
    unsigned u = __float_as_uint(f);
    return (u + 0x7fffu + ((u >> 16) & 1u)) >> 16;
}
__device__ __forceinline__ unsigned pack2(float a, float b) {
    return b16(a) | (b16(b) << 16);
}

typedef __attribute__((ext_vector_type(8))) short bf16x8;   // MFMA A/B frag (4 VGPRs)
typedef __attribute__((ext_vector_type(4))) float f32x4;    // MFMA C/D frag

// ---------------------------------------------------------------------------
// K1: bucket histogram (4096 edges/block) + classifier-collapse prep (last
// block).
//   wsu[0..15]  = w2_l[j,:].wc[:128]    wsu[16..31] = w2_l[j,:].wc[128:]
//   wsu[32..47] = w2_r[j,:].wc[:128]    wsu[48..63] = w2_r[j,:].wc[128:]
//   wsu[64] = b2.wc[:128] + bc ;  wsu[65] = b2.wc[128:]
// ---------------------------------------------------------------------------
__global__ __launch_bounds__(256) void k_bcount(const int* __restrict__ dst,
                                                int* __restrict__ bcnt,
                                                int E4, int NB, int cblocks,
                                                const float* __restrict__ w2l,
                                                const float* __restrict__ w2r,
                                                const float* __restrict__ b2v,
                                                const float* __restrict__ wc,
                                                const float* __restrict__ bc,
                                                float* __restrict__ wsu) {
    if (blockIdx.x == (unsigned)cblocks) {      // prep block
        int t = threadIdx.x;
        if (t < 64) {
            int k = t >> 4, j = t & 15;
            const float* W = (k < 2) ? w2l : w2r;
            int off = (k & 1) * DD;
            float s = 0.f;
            for (int d = 0; d < DD; ++d) s += W[j * DD + d] * wc[off + d];
            wsu[k * 16 + j] = s;
        } else if (t == 64) {
            float s = bc[0];
            for (int d = 0; d < DD; ++d) s += b2v[d] * wc[d];
            wsu[64] = s;
        } else if (t == 65) {
            float s = 0.f;
            for (int d = 0; d < DD; ++d) s += b2v[d] * wc[DD + d];
            wsu[65] = s;
        }
        return;
    }
    __shared__ int hist[NBMAX];
    for (int i = threadIdx.x; i < NB; i += 256) hist[i] = 0;
    __syncthreads();
    int base = blockIdx.x * 1024;
#pragma unroll
    for (int k = 0; k < 4; ++k) {
        int i4 = base + k * 256 + threadIdx.x;
        if (i4 < E4) {
            int4 d = ((const int4*)dst)[i4];
            atomicAdd(&hist[d.x >> 7], 1);
            atomicAdd(&hist[d.y >> 7], 1);
            atomicAdd(&hist[d.z >> 7], 1);
            atomicAdd(&hist[d.w >> 7], 1);
        }
    }
    __syncthreads();
    for (int i = threadIdx.x; i < NB; i += 256) {
        int h = hist[i];
        if (h) atomicAdd(&bcnt[i], h);
    }
}

// ---------------------------------------------------------------------------
// K2: exclusive scan over NB bucket counts -> bstart (+[NB]=E), gcursor;
// also nodestart[N] = E. Single block of 1024.
// ---------------------------------------------------------------------------
__global__ __launch_bounds__(1024) void k_bscan(const int* __restrict__ bcnt,
                                                int* __restrict__ bstart,
                                                int* __restrict__ gcursor,
                                                int* __restrict__ nodestart,
                                                int NB, int N, int E) {
    __shared__ int sa[1024];
    __shared__ int sb[1024];
    int t = threadIdx.x;
    int v = (t < NB) ? bcnt[t] : 0;
    sa[t] = v;
    __syncthreads();
    int* cur = sa;
    int* nxt = sb;
    for (int off = 1; off < 1024; off <<= 1) {
        int xv = cur[t];
        if (t >= off) xv += cur[t - off];
        nxt[t] = xv;
        __syncthreads();
        int* tmp = cur; cur = nxt; nxt = tmp;
    }
    if (t < NB) {
        int excl = cur[t] - v;
        bstart[t] = excl;
        gcursor[t] = excl;
    }
    if (t == 0) {
        bstart[NB] = cur[1023];
        nodestart[N] = E;
    }
}

// ---------------------------------------------------------------------------
// K3: bucketed scatter (4096 edges/block). LDS hist -> bulk range
// reservation -> packed entries (local<<20 | src) into per-bucket ranges.
// ---------------------------------------------------------------------------
__global__ __launch_bounds__(256) void k_bscatter(const int* __restrict__ src,
                                                  const int* __restrict__ dst,
                                                  int* __restrict__ gcursor,
                                                  int* __restrict__ packed,
                                                  int E4, int NB) {
    __shared__ int hist[NBMAX];
    __shared__ int cur[NBMAX];
    for (int i = threadIdx.x; i < NB; i += 256) hist[i] = 0;
    __syncthreads();
    int base = blockIdx.x * 1024;
    int4 dreg[4];
#pragma unroll
    for (int k = 0; k < 4; ++k) {
        int i4 = base + k * 256 + threadIdx.x;
        if (i4 < E4) {
            int4 d = ((const int4*)dst)[i4];
            dreg[k] = d;
            atomicAdd(&hist[d.x >> 7], 1);
            atomicAdd(&hist[d.y >> 7], 1);
            atomicAdd(&hist[d.z >> 7], 1);
            atomicAdd(&hist[d.w >> 7], 1);
        }
    }
    __syncthreads();
    for (int i = threadIdx.x; i < NB; i += 256) {
        int hv = hist[i];
        cur[i] = hv ? atomicAdd(&gcursor[i], hv) : 0;
    }
    __syncthreads();
#pragma unroll
    for (int k = 0; k < 4; ++k) {
        int i4 = base + k * 256 + threadIdx.x;
        if (i4 < E4) {
            int4 sv = ((const int4*)src)[i4];
            int4 d = dreg[k];
            int p;
            p = atomicAdd(&cur[d.x >> 7], 1); packed[p] = ((d.x & 127) << 20) | sv.x;
            p = atomicAdd(&cur[d.y >> 7], 1); packed[p] = ((d.y & 127) << 20) | sv.y;
            p = atomicAdd(&cur[d.z >> 7], 1); packed[p] = ((d.z & 127) << 20) | sv.z;
            p = atomicAdd(&cur[d.w >> 7], 1); packed[p] = ((d.w & 127) << 20) | sv.w;
        }
    }
}

// ---------------------------------------------------------------------------
// K4: y1 = x @ w1_l (bf16 out), z1 = x @ w1_r (f32 out) via MFMA.
// D[n][m] = sum_k W[k][n] * x[m][k] : A = W^T frags (preloaded per wave),
// B = x-row frags. One 16-row tile per wave per iter, 8 MFMAs/tile
// (4 ksteps x 2 matrices), 1-deep tile prefetch. C/D layout (verified):
// col=lane&15 = x-row m, row=quad*4+reg = output col n -> lane writes
// y1[m][4q..4q+3] as uint2 and z1[m][4q..4q+3] as float4 (coalesced).
// ---------------------------------------------------------------------------
__global__ __launch_bounds__(256) void k_xform(const float* __restrict__ x,
                                               const float* __restrict__ w1l,
                                               const float* __restrict__ w1r,
                                               unsigned* __restrict__ y1b,
                                               float* __restrict__ z1, int N) {
    const int lane = threadIdx.x & 63;
    const int m    = lane & 15;    // A-operand: output col n ; B-operand: x row m
    const int quad = lane >> 4;    // 0..3
    const int wid  = (int)((blockIdx.x * 256 + threadIdx.x) >> 6);
    const int nw   = (int)((gridDim.x * 256) >> 6);
    const int ntiles = N >> 4;

    // A-frags: A[n=lane&15][k=quad*8+j] = W[kk*32+quad*8+j][n]
    bf16x8 AL[4], AR[4];
#pragma unroll
    for (int kk = 0; kk < 4; ++kk) {
        union { unsigned u[4]; bf16x8 v; } al, ar;
#pragma unroll
        for (int p = 0; p < 4; ++p) {
            int d0 = kk * 32 + quad * 8 + 2 * p;
            al.u[p] = pack2(w1l[(size_t)d0 * HH + m], w1l[(size_t)(d0 + 1) * HH + m]);
            ar.u[p] = pack2(w1r[(size_t)d0 * HH + m], w1r[(size_t)(d0 + 1) * HH + m]);
        }
        AL[kk] = al.v; AR[kk] = ar.v;
    }

    const float4* xg = (const float4*)x;
    int tile = wid;
    if (tile < ntiles) {
        float4 cx[8];
#pragma unroll
        for (int kk = 0; kk < 4; ++kk) {
            size_t o = (size_t)(tile * 16 + m) * 32 + kk * 8 + quad * 2;
            cx[kk * 2]     = xg[o];
            cx[kk * 2 + 1] = xg[o + 1];
        }
        while (tile < ntiles) {
            int ntile = tile + nw;
            float4 nx[8];
            if (ntile < ntiles) {
#pragma unroll
                for (int kk = 0; kk < 4; ++kk) {
                    size_t o = (size_t)(ntile * 16 + m) * 32 + kk * 8 + quad * 2;
                    nx[kk * 2]     = xg[o];
                    nx[kk * 2 + 1] = xg[o + 1];
                }
            }
            f32x4 accL = {0.f, 0.f, 0.f, 0.f};
            f32x4 accR = {0.f, 0.f, 0.f, 0.f};
#pragma unroll
            for (int kk = 0; kk < 4; ++kk) {
                union { unsigned u[4]; bf16x8 v; } bx;
                float4 a = cx[kk * 2], b = cx[kk * 2 + 1];
                bx.u[0] = pack2(a.x, a.y);
                bx.u[1] = pack2(a.z, a.w);
                bx.u[2] = pack2(b.x, b.y);
                bx.u[3] = pack2(b.z, b.w);
                accL = __builtin_amdgcn_mfma_f32_16x16x32_bf16(AL[kk], bx.v, accL, 0, 0, 0);
                accR = __builtin_amdgcn_mfma_f32_16x16x32_bf16(AR[kk], bx.v, accR, 0, 0, 0);
            }
            int row = tile * 16 + m;
            uint2 yp; yp.x = pack2(accL[0], accL[1]); yp.y = pack2(accL[2], accL[3]);
            ((uint2*)y1b)[(size_t)row * 4 + quad] = yp;
            float4 zf = {accR[0], accR[1], accR[2], accR[3]};
            ((float4*)z1)[(size_t)row * 4 + quad] = zf;
            tile = ntile;
#pragma unroll
            for (int i = 0; i < 8; ++i) cx[i] = nx[i];
        }
    }

    // scalar tail for N % 16 (not hit when N % 16 == 0)
    const int tail0 = ntiles << 4;
    if (tail0 < N && blockIdx.x == 0) {
        for (int idx = threadIdx.x; idx < (N - tail0) * HH; idx += 256) {
            int row = tail0 + (idx >> 4), n = idx & 15;
            float sl = 0.f, sr = 0.f;
            for (int d = 0; d < DD; ++d) {
                float xv = x[(size_t)row * DD + d];
                sl += xv * w1l[(size_t)d * HH + n];
                sr += xv * w1r[(size_t)d * HH + n];
            }
            ((unsigned short*)y1b)[(size_t)row * 16 + n] = (unsigned short)b16(sl);
            z1[(size_t)row * HH + n] = sr;
        }
    }
}

// ---------------------------------------------------------------------------
// K5: one block per bucket.
//   Phase A: counting-sort the bucket slice in LDS, write nodestart + csr.
//   Phase B: layer-1 mean for the bucket's 128 nodes from the LDS-sorted
//            slice, gathering bf16 y1 (8 B/gather):
//            h = relu(mean(y1[nbrs]) + b1 + z1), h stored bf16.
// Global fallback for oversized buckets.
// ---------------------------------------------------------------------------
__global__ __launch_bounds__(256) void k_sortagg(const int* __restrict__ packed,
                                                 const int* __restrict__ bstart,
                                                 int* __restrict__ nodestart,
                                                 int* __restrict__ csr,
                                                 const unsigned* __restrict__ y1b,
                                                 const float* __restrict__ z1,
                                                 const float* __restrict__ b1,
                                                 unsigned* __restrict__ hb, int N) {
    __shared__ int buf[SCAP];
    __shared__ int sbuf[SCAP];
    __shared__ int hist[BW];
    __shared__ int exs[BW];
    __shared__ int curs[BW];
    __shared__ int wtot;
    const int tid = threadIdx.x;
    const int b = blockIdx.x;
    const int st = bstart[b], en = bstart[b + 1], cnt = en - st;
    const bool inlds = (cnt <= SCAP);

    if (tid < BW) hist[tid] = 0;
    __syncthreads();
    if (inlds) {
        for (int i = tid; i < cnt; i += 256) {
            int e = packed[st + i];
            buf[i] = e;
            atomicAdd(&hist[e >> 20], 1);
        }
    } else {
        for (int i = tid; i < cnt; i += 256)
            atomicAdd(&hist[packed[st + i] >> 20], 1);
    }
    __syncthreads();

    int v = 0, s = 0;
    if (tid < BW) {
        int lane = tid & 63;
        v = hist[tid];
        s = v;
#pragma unroll
        for (int off = 1; off < 64; off <<= 1) {
            int u = __shfl_up(s, off, 64);
            if (lane >= off) s += u;
        }
        if (tid == 63) wtot = s;
    }
    __syncthreads();
    if (tid < BW) {
        int ex = s - v + ((tid >= 64) ? wtot : 0);
        exs[tid] = ex;
        curs[tid] = ex;
        int node = (b << 7) + tid;
        if (node < N) nodestart[node] = st + ex;
    }
    __syncthreads();

    if (inlds) {
        for (int i = tid; i < cnt; i += 256) {
            int e = buf[i];
            int p = atomicAdd(&curs[e >> 20], 1);
            sbuf[p] = e & 0xFFFFF;
        }
        __syncthreads();
        for (int i = tid; i < cnt; i += 256) csr[st + i] = sbuf[i];  // coalesced
    } else {
        for (int i = tid; i < cnt; i += 256) {
            int e = packed[st + i];
            int p = atomicAdd(&curs[e >> 20], 1);
            csr[st + p] = e & 0xFFFFF;
        }
        __threadfence_block();
        __syncthreads();
    }

    // ---- Phase B: aggregate 128 nodes (4 lanes/node, 2 halves) ----
    const uint2* f2 = (const uint2*)y1b;
#pragma unroll
    for (int half = 0; half < 2; ++half) {
        int l = (tid >> 2) + half * 64;
        int seg = tid & 3;
        int node = (b << 7) + l;
        if (node < N) {
            int s0 = exs[l], c = hist[l];
            float ax = 0.f, ay = 0.f, az = 0.f, aw = 0.f;
            int k = 0;
            if (inlds) {
                for (; k + 4 <= c; k += 4) {
                    uint2 a = f2[(size_t)(sbuf[s0 + k]     * 4 + seg)];
                    uint2 bv = f2[(size_t)(sbuf[s0 + k + 1] * 4 + seg)];
                    uint2 cv = f2[(size_t)(sbuf[s0 + k + 2] * 4 + seg)];
                    uint2 dv = f2[(size_t)(sbuf[s0 + k + 3] * 4 + seg)];
                    ax += (lo16(a.x) + lo16(bv.x)) + (lo16(cv.x) + lo16(dv.x));
                    ay += (hi16(a.x) + hi16(bv.x)) + (hi16(cv.x) + hi16(dv.x));
                    az += (lo16(a.y) + lo16(bv.y)) + (lo16(cv.y) + lo16(dv.y));
                    aw += (hi16(a.y) + hi16(bv.y)) + (hi16(cv.y) + hi16(dv.y));
                }
                for (; k < c; ++k) {
                    uint2 a = f2[(size_t)(sbuf[s0 + k] * 4 + seg)];
                    ax += lo16(a.x); ay += hi16(a.x);
                    az += lo16(a.y); aw += hi16(a.y);
                }
            } else {
                const int* ids = csr + st + s0;
                for (; k + 4 <= c; k += 4) {
                    uint2 a = f2[(size_t)(ids[k]     * 4 + seg)];
                    uint2 bv = f2[(size_t)(ids[k + 1] * 4 + seg)];
                    uint2 cv = f2[(size_t)(ids[k + 2] * 4 + seg)];
                    uint2 dv = f2[(size_t)(ids[k + 3] * 4 + seg)];
                    ax += (lo16(a.x) + lo16(bv.x)) + (lo16(cv.x) + lo16(dv.x));
                    ay += (hi16(a.x) + hi16(bv.x)) + (hi16(cv.x) + hi16(dv.x));
                    az += (lo16(a.y) + lo16(bv.y)) + (lo16(cv.y) + lo16(dv.y));
                    aw += (hi16(a.y) + hi16(bv.y)) + (hi16(cv.y) + hi16(dv.y));
                }
                for (; k < c; ++k) {
                    uint2 a = f2[(size_t)(ids[k] * 4 + seg)];
                    ax += lo16(a.x); ay += hi16(a.x);
                    az += lo16(a.y); aw += hi16(a.y);
                }
            }
            float inv = 1.f / fmaxf((float)c, 1.f);
            size_t o = (size_t)node * 4 + seg;
            float4 z = ((const float4*)z1)[o];
            float4 bb = ((const float4*)b1)[seg];
            float hx = fmaxf(ax * inv + bb.x + z.x, 0.f);
            float hy = fmaxf(ay * inv + bb.y + z.y, 0.f);
            float hz = fmaxf(az * inv + bb.z + z.z, 0.f);
            float hw = fmaxf(aw * inv + bb.w + z.w, 0.f);
            uint2 hp; hp.x = pack2(hx, hy); hp.y = pack2(hz, hw);
            ((uint2*)hb)[o] = hp;
        }
    }
}

// ---------------------------------------------------------------------------
// K6: fused layer-2 on-demand aggregation + pair logits + BCE + final mean
// (ticket). 8 lanes per pair: slot s=sub>>2 (article), seg=sub&3. Gathers
// bf16 h (8 B per edge per lane).
// ---------------------------------------------------------------------------
__global__ __launch_bounds__(256) void k_pair(const unsigned* __restrict__ hb,
                                              const int* __restrict__ csr,
                                              const int* __restrict__ nodestart,
                                              const int* __restrict__ a1,
                                              const int* __restrict__ a2,
                                              const int* __restrict__ labels,
                                              const float* __restrict__ wsu,
                                              float* __restrict__ out_logits,
                                              float* __restrict__ lacc,
                                              int* __restrict__ ticket,
                                              float* __restrict__ out0,
                                              int B, float invB) {
    __shared__ float lred[32];
    int t = blockIdx.x * 256 + threadIdx.x;
    int p = t >> 3, sub = t & 7;
    int s = sub >> 2, seg = sub & 3;
    int g = threadIdx.x >> 3;
    const uint2* h2 = (const uint2*)hb;
    const float4* wsu4 = (const float4*)wsu;

    float myloss = 0.f;
    if (p < B) {
        int node = s ? a2[p] : a1[p];
        int st = nodestart[node], en = nodestart[node + 1];
        float ax = 0.f, ay = 0.f, az = 0.f, aw = 0.f;
        int k = st;
        for (; k + 2 <= en; k += 2) {
            uint2 a = h2[(size_t)(csr[k]     * 4 + seg)];
            uint2 b = h2[(size_t)(csr[k + 1] * 4 + seg)];
            ax += lo16(a.x) + lo16(b.x); ay += hi16(a.x) + hi16(b.x);
            az += lo16(a.y) + lo16(b.y); aw += hi16(a.y) + hi16(b.y);
        }
        if (k < en) {
            uint2 a = h2[(size_t)(csr[k] * 4 + seg)];
            ax += lo16(a.x); ay += hi16(a.x);
            az += lo16(a.y); aw += hi16(a.y);
        }
        float inv = 1.f / fmaxf((float)(en - st), 1.f);
        float4 ul = wsu4[s * 4 + seg];
        float4 ur = wsu4[8 + s * 4 + seg];
        uint2 hn = h2[(size_t)node * 4 + seg];
        float v = (ax * ul.x + ay * ul.y + az * ul.z + aw * ul.w) * inv
                + (lo16(hn.x) * ur.x + hi16(hn.x) * ur.y
                 + lo16(hn.y) * ur.z + hi16(hn.y) * ur.w);
#pragma unroll
        for (int off = 4; off; off >>= 1) v += __shfl_xor(v, off, 8);
        if (sub == 0) {
            float l = v + wsu[64] + wsu[65];
            out_logits[p] = l;
            float y = (float)labels[p];
            myloss = fmaxf(l, 0.f) - l * y + log1pf(expf(-fabsf(l)));
        }
    }
    if (sub == 0) lred[g] = myloss;
    __syncthreads();
    if (threadIdx.x == 0) {
        float ssum = 0.f;
#pragma unroll
        for (int k = 0; k < 32; ++k) ssum += lred[k];
        atomicAdd(lacc, ssum);
        __threadfence();
        int tk = atomicAdd(ticket, 1);
        if (tk == (int)gridDim.x - 1) {
            __threadfence();
            float total = atomicAdd(lacc, 0.f);
            out0[0] = total * invB;
        }
    }
}

// ---------------------------------------------------------------------------
extern "C" void kernel_launch(void* const* d_in, const int* in_sizes, int n_in,
                              void* d_out, int out_size, void* d_ws, size_t ws_size,
                              hipStream_t stream) {
    const float* x    = (const float*)d_in[0];
    const float* w1l  = (const float*)d_in[1];
    const float* b1   = (const float*)d_in[2];
    const float* w1r  = (const float*)d_in[3];
    const float* w2l  = (const float*)d_in[4];
    const float* b2v  = (const float*)d_in[5];
    const float* w2r  = (const float*)d_in[6];
    const float* wc   = (const float*)d_in[7];
    const float* bc   = (const float*)d_in[8];
    const int*   ei   = (const int*)d_in[9];
    const int*   a1   = (const int*)d_in[10];
    const int*   a2   = (const int*)d_in[11];
    const int*   lab  = (const int*)d_in[12];

    const int N = in_sizes[0] / DD;
    const int E = in_sizes[9] / 2;
    const int B = in_sizes[10];
    const int NB = (N + BW - 1) / BW;       // 782 for N=100000 (needs N < 2^20)

    const int* src = ei;
    const int* dst = ei + E;

    // workspace layout
    char* ws = (char*)d_ws;
    float*    wsu    = (float*)ws;                            // 512 B
    unsigned* y1b    = (unsigned*)(ws + 512);                 // [N,16] bf16 (32 B/row)
    unsigned* hb     = (unsigned*)(ws + 512 + (size_t)N * 32);
    float*    z1     = (float*)   (ws + 512 + (size_t)N * 64);
    int*      packed = (int*)     (ws + 512 + (size_t)N * 128);
    int*      csr    = (int*)     (ws + 512 + (size_t)N * 128 + (size_t)E * 4);
    char*     p4     = ws + 512 + (size_t)N * 128 + 2 * (size_t)E * 4;
    int*   nodest  = (int*)p4;                               // [N+1]
    int*   bstart  = (int*)(p4 + ((size_t)N + 1) * 4);       // [NB+1]
    int*   gcursor = (int*)(p4 + ((size_t)N + 1) * 4 + ((size_t)NB + 1) * 4);  // [NB]
    int*   bcnt    = (int*)(p4 + ((size_t)N + 1) * 4 + (2 * (size_t)NB + 1) * 4); // [NB] zeroed
    float* lacc    = (float*)(p4 + ((size_t)N + 1) * 4 + (3 * (size_t)NB + 1) * 4);// zeroed
    int*   ticket  = (int*)((char*)lacc + 4);                // zeroed

    float* out = (float*)d_out;       // out[0] = loss, out[1..B] = logits

    hipMemsetAsync((void*)bcnt, 0, (size_t)NB * 4 + 8, stream);

    const int E4 = E / 4;
    const int cblocks = (E4 + 1023) / 1024;          // 4096 edges per chunk

    k_bcount<<<cblocks + 1, 256, 0, stream>>>(dst, bcnt, E4, NB, cblocks,
                                              w2l, w2r, b2v, wc, bc, wsu);
    k_bscan<<<1, 1024, 0, stream>>>(bcnt, bstart, gcursor, nodest, NB, N, E);
    k_bscatter<<<cblocks, 256, 0, stream>>>(src, dst, gcursor, packed, E4, NB);

    k_xform<<<512, 256, 0, stream>>>(x, w1l, w1r, y1b, z1, N);

    k_sortagg<<<NB, 256, 0, stream>>>(packed, bstart, nodest, csr, y1b, z1, b1, hb, N);

    k_pair<<<(B * 8 + 255) / 256, 256, 0, stream>>>(hb, csr, nodest, a1, a2, lab, wsu,
                                                    out + 1, lacc, ticket, out,
                                                    B, 1.0f / (float)B);
}